// Round 2
// baseline (321.434 us; speedup 1.0000x reference)
//
#include <hip/hip_runtime.h>

// Problem constants (from setup_inputs)
constexpr int BB   = 4;      // batch
constexpr int CCH  = 256;    // C
constexpr int IDIM = 128;    // I
constexpr int NAa  = 4096;   // Ha*Wa
constexpr int NDd  = 16384;  // Hd*Wd

__device__ inline void load4f(const float* p, float o[4]) {
    float4 v = *(const float4*)p;
    o[0] = v.x; o[1] = v.y; o[2] = v.z; o[3] = v.w;
}
__device__ inline void store4(float* p, float a, float b, float c, float d) {
    *(float4*)p = make_float4(a, b, c, d);
}

// ---------- generic 64x64-tile GEMM: C[z] = A[z] @ B[z] + bias[z] (bias per row m) ----------
// A: MxK row-major (lda), B: KxN row-major (ldb), C: MxN row-major (ldc).
// grid: (N/64, M/64, Z), block: 256. 4x4 per thread, K-step 16.
__global__ __launch_bounds__(256) void gemm64(
    const float* __restrict__ A, long sA, int lda,
    const float* __restrict__ Bm, long sB, int ldb,
    const float* __restrict__ bias, long sBias,
    float* __restrict__ Co, long sC, int ldc, int K)
{
    const int z = blockIdx.z;
    A += (long)z * sA; Bm += (long)z * sB; bias += (long)z * sBias; Co += (long)z * sC;
    const int n0 = blockIdx.x * 64, m0 = blockIdx.y * 64;
    __shared__ float As[16][64];
    __shared__ float Bs[16][64];
    const int t = threadIdx.x, tm = t >> 4, tn = t & 15;
    float acc[4][4] = {};
    for (int kt = 0; kt < K; kt += 16) {
        float tmp[4];
        {   // A tile: 64 rows x 16 k, stored transposed As[k][m]
            const int r = t >> 2, c4 = (t & 3) << 2;
            load4f(A + (long)(m0 + r) * lda + kt + c4, tmp);
            As[c4 + 0][r] = tmp[0]; As[c4 + 1][r] = tmp[1];
            As[c4 + 2][r] = tmp[2]; As[c4 + 3][r] = tmp[3];
        }
        {   // B tile: 16 k x 64 n
            const int r = t >> 4, c4 = (t & 15) << 2;
            load4f(Bm + (long)(kt + r) * ldb + n0 + c4, tmp);
            Bs[r][c4 + 0] = tmp[0]; Bs[r][c4 + 1] = tmp[1];
            Bs[r][c4 + 2] = tmp[2]; Bs[r][c4 + 3] = tmp[3];
        }
        __syncthreads();
        #pragma unroll
        for (int kk = 0; kk < 16; ++kk) {
            const float4 a = *(const float4*)&As[kk][tm << 2];
            const float4 b = *(const float4*)&Bs[kk][tn << 2];
            const float av[4] = {a.x, a.y, a.z, a.w};
            const float bv[4] = {b.x, b.y, b.z, b.w};
            #pragma unroll
            for (int i = 0; i < 4; ++i)
                #pragma unroll
                for (int j = 0; j < 4; ++j) acc[i][j] += av[i] * bv[j];
        }
        __syncthreads();
    }
    #pragma unroll
    for (int i = 0; i < 4; ++i) {
        const int m = m0 + (tm << 2) + i;
        const float bb = bias[m];
        store4(Co + (long)m * ldc + n0 + (tn << 2),
               acc[i][0] + bb, acc[i][1] + bb, acc[i][2] + bb, acc[i][3] + bb);
    }
}

// ---------- NT partial GEMM: Mpart[chunk][b] = ag[b](I x Kchunk) @ th[b](I x Kchunk)^T ----------
// grid: (I/64, I/64, BB*16), block 256
__global__ __launch_bounds__(256) void gemm64_nt_part(
    const float* __restrict__ AG, const float* __restrict__ TH, float* __restrict__ Mpart)
{
    const int bz = blockIdx.z;
    const int b = bz >> 4, chunk = bz & 15;
    const float* A  = AG + (long)b * IDIM * NAa;
    const float* Bt = TH + (long)b * IDIM * NAa;
    float* out = Mpart + ((long)chunk * BB + b) * IDIM * IDIM;
    const int n0 = blockIdx.x * 64, m0 = blockIdx.y * 64;
    const int kbeg = chunk * 256;
    __shared__ float As[16][64];
    __shared__ float Bs[16][64];
    const int t = threadIdx.x, tm = t >> 4, tn = t & 15;
    float acc[4][4] = {};
    for (int kt = kbeg; kt < kbeg + 256; kt += 16) {
        const int r = t >> 2, c4 = (t & 3) << 2;
        float4 va = *(const float4*)(A + (long)(m0 + r) * NAa + kt + c4);
        As[c4 + 0][r] = va.x; As[c4 + 1][r] = va.y; As[c4 + 2][r] = va.z; As[c4 + 3][r] = va.w;
        float4 vb = *(const float4*)(Bt + (long)(n0 + r) * NAa + kt + c4);
        Bs[c4 + 0][r] = vb.x; Bs[c4 + 1][r] = vb.y; Bs[c4 + 2][r] = vb.z; Bs[c4 + 3][r] = vb.w;
        __syncthreads();
        #pragma unroll
        for (int kk = 0; kk < 16; ++kk) {
            const float4 a = *(const float4*)&As[kk][tm << 2];
            const float4 bf = *(const float4*)&Bs[kk][tn << 2];
            const float av[4] = {a.x, a.y, a.z, a.w};
            const float bv[4] = {bf.x, bf.y, bf.z, bf.w};
            #pragma unroll
            for (int i = 0; i < 4; ++i)
                #pragma unroll
                for (int j = 0; j < 4; ++j) acc[i][j] += av[i] * bv[j];
        }
        __syncthreads();
    }
    #pragma unroll
    for (int i = 0; i < 4; ++i) {
        const int m = m0 + (tm << 2) + i;
        store4(out + (long)m * IDIM + n0 + (tn << 2),
               acc[i][0], acc[i][1], acc[i][2], acc[i][3]);
    }
}

// ---------- reduce 16 K-chunks of Mpart into M ----------
__global__ void reduce_m(const float* __restrict__ Mpart, float* __restrict__ M) {
    const int idx = blockIdx.x * 256 + threadIdx.x;   // < BB*I*I
    float s = 0.f;
    #pragma unroll
    for (int p = 0; p < 16; ++p) s += Mpart[(long)p * (BB * IDIM * IDIM) + idx];
    M[idx] = s;
}

// ---------- W2[b,o,j] = (1/Na) * sum_i q_w[o,i] * M[b,i,j] ----------
__global__ void w2_kernel(const float* __restrict__ qw,
                          const float* __restrict__ M, float* __restrict__ W2) {
    const int idx = blockIdx.x * 256 + threadIdx.x;   // < BB*C*I
    const int j = idx & (IDIM - 1);
    const int o = (idx >> 7) & (CCH - 1);
    const int b = idx >> 15;
    const float* Mb = M + (long)b * IDIM * IDIM;
    float acc = 0.f;
    #pragma unroll 4
    for (int i = 0; i < IDIM; ++i) acc += qw[o * IDIM + i] * Mb[i * IDIM + j];
    W2[idx] = acc * (1.0f / NAa);
}

// ---------- W5[b,o,c] = s[o]*(W2[b,o,:]·phi_w[:,c]) + (o==c); b5[b,o] = s[o]*(W2·phi_b + q_b - mean) + beta ----------
__global__ void w5_kernel(const float* __restrict__ W2,
                          const float* __restrict__ phiw,
                          const float* __restrict__ phib,
                          const float* __restrict__ qb,
                          const float* __restrict__ gamma,
                          const float* __restrict__ beta,
                          const float* __restrict__ mean,
                          const float* __restrict__ var,
                          float* __restrict__ W5, float* __restrict__ b5) {
    const int idx = blockIdx.x * 256 + threadIdx.x;   // < BB*C*C
    const int c = idx & 255;
    const int o = (idx >> 8) & 255;
    const int b = idx >> 16;
    const float* w2row = W2 + ((long)b * CCH + o) * IDIM;
    float acc = 0.f;
    #pragma unroll 4
    for (int j = 0; j < IDIM; ++j) acc += w2row[j] * phiw[j * CCH + c];
    const float s = gamma[o] * rsqrtf(var[o] + 1e-5f);
    W5[idx] = s * acc + ((o == c) ? 1.0f : 0.0f);
    if (c == 0) {
        float ab = 0.f;
        for (int j = 0; j < IDIM; ++j) ab += w2row[j] * phib[j];
        b5[b * CCH + o] = s * (ab + qb[o] - mean[o]) + beta[o];
    }
}

extern "C" void kernel_launch(void* const* d_in, const int* in_sizes, int n_in,
                              void* d_out, int out_size, void* d_ws, size_t ws_size,
                              hipStream_t stream) {
    const float* detect = (const float*)d_in[0];
    const float* aim    = (const float*)d_in[1];
    const float* g_w    = (const float*)d_in[2];
    const float* g_b    = (const float*)d_in[3];
    const float* th_w   = (const float*)d_in[4];
    const float* th_b   = (const float*)d_in[5];
    const float* phi_w  = (const float*)d_in[6];
    const float* phi_b  = (const float*)d_in[7];
    const float* q_w    = (const float*)d_in[8];
    const float* q_b    = (const float*)d_in[9];
    const float* gamma  = (const float*)d_in[10];
    const float* beta   = (const float*)d_in[11];
    const float* mean   = (const float*)d_in[12];
    const float* var    = (const float*)d_in[13];
    float* out = (float*)d_out;

    float* ws = (float*)d_ws;
    float* ag    = ws;                                  // BB*I*Na   = 2,097,152
    float* th    = ag + (long)BB * IDIM * NAa;          // 2,097,152
    float* Mpart = th + (long)BB * IDIM * NAa;          // 16*BB*I*I = 1,048,576
    float* Mred  = Mpart + 16L * BB * IDIM * IDIM;      // 65,536
    float* W2    = Mred + (long)BB * IDIM * IDIM;       // 131,072
    float* W5    = W2 + (long)BB * CCH * IDIM;          // 262,144
    float* b5    = W5 + (long)BB * CCH * CCH;           // 1,024

    dim3 blk(256);

    // 1) projections of aim: ag = g_w@A + g_b ; th = theta_w@A + theta_b
    gemm64<<<dim3(NAa / 64, IDIM / 64, BB), blk, 0, stream>>>(
        g_w, 0, CCH, aim, (long)CCH * NAa, NAa, g_b, 0,
        ag, (long)IDIM * NAa, NAa, CCH);
    gemm64<<<dim3(NAa / 64, IDIM / 64, BB), blk, 0, stream>>>(
        th_w, 0, CCH, aim, (long)CCH * NAa, NAa, th_b, 0,
        th, (long)IDIM * NAa, NAa, CCH);

    // 2) M = ag @ th^T  (K=4096 split into 16 chunks) then reduce
    gemm64_nt_part<<<dim3(IDIM / 64, IDIM / 64, BB * 16), blk, 0, stream>>>(ag, th, Mpart);
    reduce_m<<<dim3(BB * IDIM * IDIM / 256), blk, 0, stream>>>(Mpart, Mred);

    // 3) weight prep: W2 = q_w@M/Na ; W5 = diag(s)@(W2@phi_w) + I ; b5
    w2_kernel<<<dim3(BB * CCH * IDIM / 256), blk, 0, stream>>>(q_w, Mred, W2);
    w5_kernel<<<dim3(BB * CCH * CCH / 256), blk, 0, stream>>>(
        W2, phi_w, phi_b, q_b, gamma, beta, mean, var, W5, b5);

    // 4) out = W5 @ detect + b5   (residual folded into W5/b5)
    gemm64<<<dim3(NDd / 64, CCH / 64, BB), blk, 0, stream>>>(
        W5, (long)CCH * CCH, CCH, detect, (long)CCH * NDd, NDd, b5, CCH,
        out, (long)CCH * NDd, NDd, CCH);
}

// Round 3
// 249.258 us; speedup vs baseline: 1.2896x; 1.2896x over previous
//
#include <hip/hip_runtime.h>

constexpr int BB   = 4;
constexpr int CCH  = 256;
constexpr int IDIM = 128;
constexpr int NAa  = 4096;
constexpr int NDd  = 16384;
constexpr int PAD  = 320;                 // aug dim 257 padded to 320 (5x64)
constexpr float NAinv = 1.0f / 4096.0f;

typedef __bf16 bf16x8 __attribute__((ext_vector_type(8)));
typedef float  f32x4  __attribute__((ext_vector_type(4)));

__device__ inline unsigned short f2bfu(float f) {
    unsigned u = __float_as_uint(f);
    u += 0x7FFFu + ((u >> 16) & 1u);      // RNE
    return (unsigned short)(u >> 16);
}

// ---- aim fp32 -> bf16 + per-(b,c) rowsum r. grid: BB*CCH blocks of 256 ----
__global__ __launch_bounds__(256) void k_conv(const float* __restrict__ aim,
                                              unsigned short* __restrict__ Abf,
                                              float* __restrict__ r) {
    const int row = blockIdx.x;                // b*256 + c
    const float* src = aim + (long)row * NAa;
    unsigned short* dst = Abf + (long)row * NAa;
    const int t = threadIdx.x;
    float s = 0.f;
    #pragma unroll
    for (int j = 0; j < 4; ++j) {
        const int e = (j * 256 + t) * 4;
        float4 v = *(const float4*)(src + e);
        s += v.x + v.y + v.z + v.w;
        ushort4 o; o.x = f2bfu(v.x); o.y = f2bfu(v.y); o.z = f2bfu(v.z); o.w = f2bfu(v.w);
        *(ushort4*)(dst + e) = o;
    }
    __shared__ float red[256];
    red[t] = s; __syncthreads();
    for (int st = 128; st > 0; st >>= 1) { if (t < st) red[t] += red[t + st]; __syncthreads(); }
    if (t == 0) r[row] = red[0];
}

// ---- batch-independent weight products: Phat (256x320), Rhat (320x320) ----
// Phat[o][c] = sum_i q_w[o][i]*g_w[i][c] (c<256) | q_w.g_b (c==256) | 0
// Rhat[k][c2]= sum_i th_w[i][k]*phi_w[i][c2] with k==256 -> th_b, c2==256 -> phi_b
__global__ __launch_bounds__(256) void k_prep(const float* __restrict__ qw,
                                              const float* __restrict__ gw,
                                              const float* __restrict__ gb,
                                              const float* __restrict__ thw,
                                              const float* __restrict__ thb,
                                              const float* __restrict__ phw,
                                              const float* __restrict__ phb,
                                              float* __restrict__ Phat,
                                              float* __restrict__ Rhat) {
    const int idx = blockIdx.x * 256 + threadIdx.x;
    if (idx < CCH * PAD) {
        const int o = idx / PAD, c = idx - o * PAD;
        float acc = 0.f;
        for (int i = 0; i < IDIM; ++i) {
            const float av = qw[o * IDIM + i];
            const float bv = (c < 256) ? gw[i * CCH + c] : gb[i];
            acc += av * bv;
        }
        if (c > 256) acc = 0.f;
        Phat[idx] = acc;
    } else {
        const int id2 = idx - CCH * PAD;
        const int k = id2 / PAD, c2 = id2 - k * PAD;
        float acc = 0.f;
        for (int i = 0; i < IDIM; ++i) {
            const float av = (k < 256) ? thw[i * CCH + k] : thb[i];
            const float bv = (c2 < 256) ? phw[i * CCH + c2] : phb[i];
            acc += av * bv;
        }
        if (k > 256 || c2 > 256) acc = 0.f;
        Rhat[id2] = acc;
    }
}

// ---- S partials: Spart[z] = A[b] @ A[b]^T over K-chunk. grid (2,2,BB*8) ----
__global__ __launch_bounds__(256) void k_S(const unsigned short* __restrict__ Abf,
                                           float* __restrict__ Spart) {
    const int z = blockIdx.z, b = z >> 3, chunk = z & 7;
    const unsigned short* A = Abf + (long)b * CCH * NAa;
    const int t = threadIdx.x, w = t >> 6, lane = t & 63, quad = lane >> 4, l16 = lane & 15;
    const int mb = blockIdx.y * 128 + (w >> 1) * 64;
    const int nb = blockIdx.x * 128 + (w & 1) * 64;
    const int kbase = chunk * 512;
    f32x4 acc[4][4] = {};
    for (int ks = 0; ks < 16; ++ks) {
        const int k = kbase + ks * 32 + quad * 8;
        bf16x8 af[4], bfr[4];
        #pragma unroll
        for (int i = 0; i < 4; ++i) af[i]  = *(const bf16x8*)(A + (long)(mb + i * 16 + l16) * NAa + k);
        #pragma unroll
        for (int j = 0; j < 4; ++j) bfr[j] = *(const bf16x8*)(A + (long)(nb + j * 16 + l16) * NAa + k);
        #pragma unroll
        for (int i = 0; i < 4; ++i)
            #pragma unroll
            for (int j = 0; j < 4; ++j)
                acc[i][j] = __builtin_amdgcn_mfma_f32_16x16x32_bf16(af[i], bfr[j], acc[i][j], 0, 0, 0);
    }
    float* out = Spart + (long)z * CCH * CCH;
    #pragma unroll
    for (int i = 0; i < 4; ++i)
        #pragma unroll
        for (int j = 0; j < 4; ++j)
            #pragma unroll
            for (int reg = 0; reg < 4; ++reg)
                out[(long)(mb + i * 16 + quad * 4 + reg) * CCH + nb + j * 16 + l16] = acc[i][j][reg];
}

// ---- assemble Shat (320x320 per batch): [[sum Spart, r],[r^T, Na]], zero pad ----
__global__ __launch_bounds__(256) void k_red(const float* __restrict__ Spart,
                                             const float* __restrict__ r,
                                             float* __restrict__ Shat) {
    const int b = blockIdx.y;
    const int idx = blockIdx.x * 256 + threadIdx.x;     // < 320*320
    const int k = idx / PAD, n = idx - k * PAD;
    float v = 0.f;
    if (k < 256 && n < 256) {
        #pragma unroll
        for (int p = 0; p < 8; ++p)
            v += Spart[(long)(b * 8 + p) * CCH * CCH + k * CCH + n];
    } else if (k == 256 && n < 256) v = r[b * CCH + n];
    else if (n == 256 && k < 256)   v = r[b * CCH + k];
    else if (k == 256 && n == 256)  v = 4096.0f;
    Shat[(long)b * PAD * PAD + idx] = v;
}

// ---- That[b] = Phat(256x320) @ Shat[b](320x320). grid (5,4,BB) ----
__global__ __launch_bounds__(256) void k_T(const float* __restrict__ Phat,
                                           const float* __restrict__ Shat,
                                           float* __restrict__ That) {
    const int b = blockIdx.z;
    const float* Bm = Shat + (long)b * PAD * PAD;
    float* Co = That + (long)b * CCH * PAD;
    const int n0 = blockIdx.x * 64, m0 = blockIdx.y * 64;
    __shared__ float As[16][64], Bs[16][64];
    const int t = threadIdx.x, tm = t >> 4, tn = t & 15;
    float acc[4][4] = {};
    for (int kt = 0; kt < PAD; kt += 16) {
        { const int rr = t >> 2, c4 = (t & 3) << 2;
          float4 v = *(const float4*)(Phat + (long)(m0 + rr) * PAD + kt + c4);
          As[c4][rr] = v.x; As[c4 + 1][rr] = v.y; As[c4 + 2][rr] = v.z; As[c4 + 3][rr] = v.w; }
        { const int rr = t >> 4, c4 = (t & 15) << 2;
          float4 v = *(const float4*)(Bm + (long)(kt + rr) * PAD + n0 + c4);
          Bs[rr][c4] = v.x; Bs[rr][c4 + 1] = v.y; Bs[rr][c4 + 2] = v.z; Bs[rr][c4 + 3] = v.w; }
        __syncthreads();
        #pragma unroll
        for (int kk = 0; kk < 16; ++kk) {
            const float4 a = *(const float4*)&As[kk][tm << 2];
            const float4 bq = *(const float4*)&Bs[kk][tn << 2];
            const float av[4] = {a.x, a.y, a.z, a.w};
            const float bv[4] = {bq.x, bq.y, bq.z, bq.w};
            #pragma unroll
            for (int i = 0; i < 4; ++i)
                #pragma unroll
                for (int j = 0; j < 4; ++j) acc[i][j] += av[i] * bv[j];
        }
        __syncthreads();
    }
    #pragma unroll
    for (int i = 0; i < 4; ++i)
        *(float4*)(Co + (long)(m0 + tm * 4 + i) * PAD + n0 + tn * 4) =
            make_float4(acc[i][0], acc[i][1], acc[i][2], acc[i][3]);
}

// ---- W5 = diag(s)/Na*(That@Rhat)+I (bf16), col 256 -> b5. grid (5,4,BB) ----
__global__ __launch_bounds__(256) void k_w5(const float* __restrict__ That,
                                            const float* __restrict__ Rhat,
                                            const float* __restrict__ qb,
                                            const float* __restrict__ gamma,
                                            const float* __restrict__ beta,
                                            const float* __restrict__ mean,
                                            const float* __restrict__ var,
                                            unsigned short* __restrict__ W5u,
                                            float* __restrict__ b5) {
    const int b = blockIdx.z;
    const float* A = That + (long)b * CCH * PAD;
    const int n0 = blockIdx.x * 64, m0 = blockIdx.y * 64;
    __shared__ float As[16][64], Bs[16][64];
    const int t = threadIdx.x, tm = t >> 4, tn = t & 15;
    float acc[4][4] = {};
    for (int kt = 0; kt < PAD; kt += 16) {
        { const int rr = t >> 2, c4 = (t & 3) << 2;
          float4 v = *(const float4*)(A + (long)(m0 + rr) * PAD + kt + c4);
          As[c4][rr] = v.x; As[c4 + 1][rr] = v.y; As[c4 + 2][rr] = v.z; As[c4 + 3][rr] = v.w; }
        { const int rr = t >> 4, c4 = (t & 15) << 2;
          float4 v = *(const float4*)(Rhat + (long)(kt + rr) * PAD + n0 + c4);
          Bs[rr][c4] = v.x; Bs[rr][c4 + 1] = v.y; Bs[rr][c4 + 2] = v.z; Bs[rr][c4 + 3] = v.w; }
        __syncthreads();
        #pragma unroll
        for (int kk = 0; kk < 16; ++kk) {
            const float4 a = *(const float4*)&As[kk][tm << 2];
            const float4 bq = *(const float4*)&Bs[kk][tn << 2];
            const float av[4] = {a.x, a.y, a.z, a.w};
            const float bv[4] = {bq.x, bq.y, bq.z, bq.w};
            #pragma unroll
            for (int i = 0; i < 4; ++i)
                #pragma unroll
                for (int j = 0; j < 4; ++j) acc[i][j] += av[i] * bv[j];
        }
        __syncthreads();
    }
    #pragma unroll
    for (int i = 0; i < 4; ++i) {
        const int o = m0 + tm * 4 + i;
        const float s = gamma[o] * rsqrtf(var[o] + 1e-5f);
        #pragma unroll
        for (int j = 0; j < 4; ++j) {
            const int c2 = n0 + tn * 4 + j;
            const float val = acc[i][j] * s * NAinv;
            if (c2 < CCH)
                W5u[((long)b * CCH + o) * CCH + c2] = f2bfu(val + (o == c2 ? 1.0f : 0.0f));
            else if (c2 == CCH)
                b5[b * CCH + o] = val + s * (qb[o] - mean[o]) + beta[o];
        }
    }
}

// ---- out = W5 @ detect + b5 (MFMA bf16, fp32 out). grid (128, 2, BB) ----
__global__ __launch_bounds__(256) void k_final(const float* __restrict__ detect,
                                               const unsigned short* __restrict__ W5u,
                                               const float* __restrict__ b5,
                                               float* __restrict__ out) {
    const int z = blockIdx.z;
    const int nb = blockIdx.x * 128;
    const int ob = blockIdx.y * 128;
    const float* D = detect + (long)z * CCH * NDd;
    float* O = out + (long)z * CCH * NDd;
    const unsigned short* W = W5u + (long)z * CCH * CCH;
    const int t = threadIdx.x, w = t >> 6, lane = t & 63, quad = lane >> 4, l16 = lane & 15;
    const int mw = (w >> 1) * 64, nw = (w & 1) * 64;
    __shared__ __align__(16) unsigned short lb[128][40];   // [n][k], 80B rows (16B-aligned)
    f32x4 acc[4][4] = {};
    const int r2 = t >> 4, g = t & 15;
    for (int kt = 0; kt < CCH; kt += 32) {
        #pragma unroll
        for (int e2 = 0; e2 < 2; ++e2) {
            const int nn = g * 8 + e2 * 4;
            float4 x0 = *(const float4*)(D + (long)(kt + 2 * r2) * NDd + nb + nn);
            float4 x1 = *(const float4*)(D + (long)(kt + 2 * r2 + 1) * NDd + nb + nn);
            *(unsigned*)&lb[nn    ][2 * r2] = (unsigned)f2bfu(x0.x) | ((unsigned)f2bfu(x1.x) << 16);
            *(unsigned*)&lb[nn + 1][2 * r2] = (unsigned)f2bfu(x0.y) | ((unsigned)f2bfu(x1.y) << 16);
            *(unsigned*)&lb[nn + 2][2 * r2] = (unsigned)f2bfu(x0.z) | ((unsigned)f2bfu(x1.z) << 16);
            *(unsigned*)&lb[nn + 3][2 * r2] = (unsigned)f2bfu(x0.w) | ((unsigned)f2bfu(x1.w) << 16);
        }
        __syncthreads();
        bf16x8 af[4], bfr[4];
        #pragma unroll
        for (int i = 0; i < 4; ++i)
            af[i] = *(const bf16x8*)(W + (long)(ob + mw + i * 16 + l16) * CCH + kt + quad * 8);
        #pragma unroll
        for (int j = 0; j < 4; ++j)
            bfr[j] = *(const bf16x8*)(&lb[nw + j * 16 + l16][quad * 8]);
        #pragma unroll
        for (int i = 0; i < 4; ++i)
            #pragma unroll
            for (int j = 0; j < 4; ++j)
                acc[i][j] = __builtin_amdgcn_mfma_f32_16x16x32_bf16(af[i], bfr[j], acc[i][j], 0, 0, 0);
        __syncthreads();
    }
    #pragma unroll
    for (int i = 0; i < 4; ++i) {
        float bv[4];
        #pragma unroll
        for (int reg = 0; reg < 4; ++reg)
            bv[reg] = b5[z * CCH + ob + mw + i * 16 + quad * 4 + reg];
        #pragma unroll
        for (int j = 0; j < 4; ++j) {
            const int n = nb + nw + j * 16 + l16;
            #pragma unroll
            for (int reg = 0; reg < 4; ++reg)
                O[(long)(ob + mw + i * 16 + quad * 4 + reg) * NDd + n] = acc[i][j][reg] + bv[reg];
        }
    }
}

extern "C" void kernel_launch(void* const* d_in, const int* in_sizes, int n_in,
                              void* d_out, int out_size, void* d_ws, size_t ws_size,
                              hipStream_t stream) {
    const float* detect = (const float*)d_in[0];
    const float* aim    = (const float*)d_in[1];
    const float* g_w    = (const float*)d_in[2];
    const float* g_b    = (const float*)d_in[3];
    const float* th_w   = (const float*)d_in[4];
    const float* th_b   = (const float*)d_in[5];
    const float* phi_w  = (const float*)d_in[6];
    const float* phi_b  = (const float*)d_in[7];
    const float* q_w    = (const float*)d_in[8];
    const float* q_b    = (const float*)d_in[9];
    const float* gamma  = (const float*)d_in[10];
    const float* beta   = (const float*)d_in[11];
    const float* mean   = (const float*)d_in[12];
    const float* var    = (const float*)d_in[13];
    float* out = (float*)d_out;

    float* ws = (float*)d_ws;
    unsigned short* Abf = (unsigned short*)ws;          // 4*256*4096 us = 2,097,152 f
    float* r     = ws + 2097152;                        // 1024
    float* Spart = r + 1024;                            // 8*4*65536 = 2,097,152
    float* Shat  = Spart + 2097152;                     // 4*320*320 = 409,600
    float* Phat  = Shat + 409600;                       // 256*320   = 81,920
    float* Rhat  = Phat + 81920;                        // 320*320   = 102,400
    float* That  = Rhat + 102400;                       // 4*256*320 = 327,680
    unsigned short* W5u = (unsigned short*)(That + 327680); // 4*65536 us = 131,072 f
    float* b5    = That + 327680 + 131072;              // 1024

    dim3 blk(256);
    k_prep<<<dim3((CCH * PAD + PAD * PAD) / 256), blk, 0, stream>>>(
        q_w, g_w, g_b, th_w, th_b, phi_w, phi_b, Phat, Rhat);
    k_conv<<<dim3(BB * CCH), blk, 0, stream>>>(aim, Abf, r);
    k_S<<<dim3(2, 2, BB * 8), blk, 0, stream>>>(Abf, Spart);
    k_red<<<dim3(PAD * PAD / 256, BB), blk, 0, stream>>>(Spart, r, Shat);
    k_T<<<dim3(5, 4, BB), blk, 0, stream>>>(Phat, Shat, That);
    k_w5<<<dim3(5, 4, BB), blk, 0, stream>>>(That, Rhat, q_b, gamma, beta, mean, var, W5u, b5);
    k_final<<<dim3(NDd / 128, CCH / 128, BB), blk, 0, stream>>>(detect, W5u, b5, out);
}

// Round 4
// 218.324 us; speedup vs baseline: 1.4723x; 1.1417x over previous
//
#include <hip/hip_runtime.h>

constexpr int BB   = 4;
constexpr int CCH  = 256;
constexpr int IDIM = 128;
constexpr int NAa  = 4096;
constexpr int NDd  = 16384;
constexpr int PAD  = 320;                 // aug dim 257 padded to 320
constexpr float NAinv = 1.0f / 4096.0f;

typedef __bf16 bf16x8 __attribute__((ext_vector_type(8)));
typedef float  f32x4  __attribute__((ext_vector_type(4)));

__device__ inline unsigned short f2bfu(float f) {
    unsigned u = __float_as_uint(f);
    u += 0x7FFFu + ((u >> 16) & 1u);      // RNE
    return (unsigned short)(u >> 16);
}

// ---- aim fp32 -> bf16 + per-(b,c) rowsum r. grid: BB*CCH blocks of 256 ----
__global__ __launch_bounds__(256) void k_conv(const float* __restrict__ aim,
                                              unsigned short* __restrict__ Abf,
                                              float* __restrict__ r) {
    const int row = blockIdx.x;
    const float* src = aim + (long)row * NAa;
    unsigned short* dst = Abf + (long)row * NAa;
    const int t = threadIdx.x;
    float s = 0.f;
    #pragma unroll
    for (int j = 0; j < 4; ++j) {
        const int e = (j * 256 + t) * 4;
        float4 v = *(const float4*)(src + e);
        s += v.x + v.y + v.z + v.w;
        ushort4 o; o.x = f2bfu(v.x); o.y = f2bfu(v.y); o.z = f2bfu(v.z); o.w = f2bfu(v.w);
        *(ushort4*)(dst + e) = o;
    }
    __shared__ float red[256];
    red[t] = s; __syncthreads();
    for (int st = 128; st > 0; st >>= 1) { if (t < st) red[t] += red[t + st]; __syncthreads(); }
    if (t == 0) r[row] = red[0];
}

// ---- Phat (256x320, bf16) and RhatT (320x320, bf16, TRANSPOSED: [c2][k]) ----
__global__ __launch_bounds__(256) void k_prep(const float* __restrict__ qw,
                                              const float* __restrict__ gw,
                                              const float* __restrict__ gb,
                                              const float* __restrict__ thw,
                                              const float* __restrict__ thb,
                                              const float* __restrict__ phw,
                                              const float* __restrict__ phb,
                                              unsigned short* __restrict__ Ph,
                                              unsigned short* __restrict__ Rt) {
    const int idx = blockIdx.x * 256 + threadIdx.x;
    if (idx < CCH * PAD) {
        const int o = idx / PAD, c = idx - o * PAD;
        float acc = 0.f;
        if (c <= 256) {
            for (int i = 0; i < IDIM; ++i)
                acc += qw[o * IDIM + i] * ((c < 256) ? gw[i * CCH + c] : gb[i]);
        }
        Ph[idx] = f2bfu(acc);
    } else {
        const int id2 = idx - CCH * PAD;
        const int c2 = id2 / PAD, k = id2 - c2 * PAD;   // row c2, col k (transposed)
        float acc = 0.f;
        if (k <= 256 && c2 <= 256) {
            for (int i = 0; i < IDIM; ++i) {
                const float av = (k < 256) ? thw[i * CCH + k] : thb[i];
                const float bv = (c2 < 256) ? phw[i * CCH + c2] : phb[i];
                acc += av * bv;
            }
        }
        Rt[id2] = f2bfu(acc);
    }
}

// ---- S partials: Spart[z] = A[b] @ A[b]^T over K-chunk. grid (4,4,BB*8), block 64 ----
__global__ __launch_bounds__(64) void k_S(const unsigned short* __restrict__ Abf,
                                          float* __restrict__ Spart) {
    const int z = blockIdx.z, b = z >> 3, chunk = z & 7;
    const unsigned short* A = Abf + (long)b * CCH * NAa;
    const int lane = threadIdx.x, quad = lane >> 4, l16 = lane & 15;
    const int mb = blockIdx.y * 64, nb = blockIdx.x * 64;
    const int kb = chunk * 512;
    f32x4 acc[4][4] = {};
    for (int ks = 0; ks < 16; ++ks) {
        const int k = kb + ks * 32 + quad * 8;
        bf16x8 af[4], bfr[4];
        #pragma unroll
        for (int i = 0; i < 4; ++i) af[i]  = *(const bf16x8*)(A + (long)(mb + i * 16 + l16) * NAa + k);
        #pragma unroll
        for (int j = 0; j < 4; ++j) bfr[j] = *(const bf16x8*)(A + (long)(nb + j * 16 + l16) * NAa + k);
        #pragma unroll
        for (int i = 0; i < 4; ++i)
            #pragma unroll
            for (int j = 0; j < 4; ++j)
                acc[i][j] = __builtin_amdgcn_mfma_f32_16x16x32_bf16(af[i], bfr[j], acc[i][j], 0, 0, 0);
    }
    float* o = Spart + (long)z * CCH * CCH;
    #pragma unroll
    for (int i = 0; i < 4; ++i)
        #pragma unroll
        for (int j = 0; j < 4; ++j)
            #pragma unroll
            for (int reg = 0; reg < 4; ++reg)
                o[(long)(mb + i * 16 + quad * 4 + reg) * CCH + nb + j * 16 + l16] = acc[i][j][reg];
}

// ---- assemble Shat (320x320 bf16, symmetric): [[sum Spart, r],[r^T, Na]] ----
__global__ __launch_bounds__(256) void k_red(const float* __restrict__ Spart,
                                             const float* __restrict__ r,
                                             unsigned short* __restrict__ Shat) {
    const int b = blockIdx.y;
    const int idx = blockIdx.x * 256 + threadIdx.x;     // < 320*320
    const int k = idx / PAD, n = idx - k * PAD;
    float v = 0.f;
    if (k < 256 && n < 256) {
        #pragma unroll
        for (int p = 0; p < 8; ++p)
            v += Spart[(long)(b * 8 + p) * CCH * CCH + k * CCH + n];
    } else if (k == 256 && n < 256) v = r[b * CCH + n];
    else if (n == 256 && k < 256)   v = r[b * CCH + k];
    else if (k == 256 && n == 256)  v = 4096.0f;
    Shat[(long)b * PAD * PAD + idx] = f2bfu(v);
}

// ---- That[b] = Phat @ Shat[b] (Shat symmetric -> B-frag reads rows). grid (5,4,BB), block 64 ----
__global__ __launch_bounds__(64) void k_t1(const unsigned short* __restrict__ Ph,
                                           const unsigned short* __restrict__ Sh,
                                           unsigned short* __restrict__ Th) {
    const int b = blockIdx.z;
    const unsigned short* S = Sh + (long)b * PAD * PAD;
    unsigned short* T = Th + (long)b * CCH * PAD;
    const int n0 = blockIdx.x * 64, m0 = blockIdx.y * 64;
    const int lane = threadIdx.x, quad = lane >> 4, l16 = lane & 15;
    f32x4 acc[4][4] = {};
    for (int kt = 0; kt < PAD; kt += 32) {
        bf16x8 af[4], bfr[4];
        #pragma unroll
        for (int i = 0; i < 4; ++i) af[i]  = *(const bf16x8*)(Ph + (long)(m0 + i * 16 + l16) * PAD + kt + quad * 8);
        #pragma unroll
        for (int j = 0; j < 4; ++j) bfr[j] = *(const bf16x8*)(S  + (long)(n0 + j * 16 + l16) * PAD + kt + quad * 8);
        #pragma unroll
        for (int i = 0; i < 4; ++i)
            #pragma unroll
            for (int j = 0; j < 4; ++j)
                acc[i][j] = __builtin_amdgcn_mfma_f32_16x16x32_bf16(af[i], bfr[j], acc[i][j], 0, 0, 0);
    }
    #pragma unroll
    for (int i = 0; i < 4; ++i)
        #pragma unroll
        for (int j = 0; j < 4; ++j)
            #pragma unroll
            for (int reg = 0; reg < 4; ++reg)
                T[(long)(m0 + i * 16 + quad * 4 + reg) * PAD + n0 + j * 16 + l16] = f2bfu(acc[i][j][reg]);
}

// ---- W5 = diag(s)/Na*(That@Rhat)+I (bf16); col 256 -> b5. grid (5,4,BB), block 64 ----
__global__ __launch_bounds__(64) void k_t2(const unsigned short* __restrict__ Th,
                                           const unsigned short* __restrict__ Rt,
                                           const float* __restrict__ qb,
                                           const float* __restrict__ gamma,
                                           const float* __restrict__ beta,
                                           const float* __restrict__ mean,
                                           const float* __restrict__ var,
                                           unsigned short* __restrict__ W5u,
                                           float* __restrict__ b5) {
    const int b = blockIdx.z;
    const unsigned short* A = Th + (long)b * CCH * PAD;
    const int n0 = blockIdx.x * 64, m0 = blockIdx.y * 64;
    const int lane = threadIdx.x, quad = lane >> 4, l16 = lane & 15;
    f32x4 acc[4][4] = {};
    for (int kt = 0; kt < PAD; kt += 32) {
        bf16x8 af[4], bfr[4];
        #pragma unroll
        for (int i = 0; i < 4; ++i) af[i]  = *(const bf16x8*)(A  + (long)(m0 + i * 16 + l16) * PAD + kt + quad * 8);
        #pragma unroll
        for (int j = 0; j < 4; ++j) bfr[j] = *(const bf16x8*)(Rt + (long)(n0 + j * 16 + l16) * PAD + kt + quad * 8);
        #pragma unroll
        for (int i = 0; i < 4; ++i)
            #pragma unroll
            for (int j = 0; j < 4; ++j)
                acc[i][j] = __builtin_amdgcn_mfma_f32_16x16x32_bf16(af[i], bfr[j], acc[i][j], 0, 0, 0);
    }
    #pragma unroll
    for (int i = 0; i < 4; ++i) {
        #pragma unroll
        for (int reg = 0; reg < 4; ++reg) {
            const int o = m0 + i * 16 + quad * 4 + reg;
            const float s = gamma[o] * rsqrtf(var[o] + 1e-5f);
            #pragma unroll
            for (int j = 0; j < 4; ++j) {
                const int c2 = n0 + j * 16 + l16;
                const float val = acc[i][j][reg] * s * NAinv;
                if (c2 < CCH)
                    W5u[((long)b * CCH + o) * CCH + c2] = f2bfu(val + (o == c2 ? 1.0f : 0.0f));
                else if (c2 == CCH)
                    b5[b * CCH + o] = val + s * (qb[o] - mean[o]) + beta[o];
            }
        }
    }
}

// ---- out = W5 @ detect + b5. Permuted-row LDS (conflict-free), double-buffered. ----
// grid (128, 2, BB), block 256
__global__ __launch_bounds__(256) void k_final(const float* __restrict__ D0,
                                               const unsigned short* __restrict__ W5u,
                                               const float* __restrict__ b5,
                                               float* __restrict__ out) {
    const int z = blockIdx.z;
    const int nb = blockIdx.x * 128;
    const int ob = blockIdx.y * 128;
    const float* D = D0 + (long)z * CCH * NDd;
    float* O = out + (long)z * CCH * NDd;
    const unsigned short* W = W5u + (long)z * CCH * CCH;
    const int t = threadIdx.x, wv = t >> 6, lane = t & 63, quad = lane >> 4, l16 = lane & 15;
    const int mw = (wv >> 1) * 64, nw = (wv & 1) * 64;
    const int r2 = t >> 4, g = t & 15;
    // logical row n -> physical row p = (n&7)*16 + (n>>3): write bank = (20g + r2)%32 (2-way, free)
    __shared__ __align__(16) unsigned short lb[2][128][40];
    f32x4 x[4];

    auto load_tile = [&](int kt) {
        const float* base = D + (long)(kt + 2 * r2) * NDd + nb + 8 * g;
        x[0] = *(const f32x4*)(base);
        x[1] = *(const f32x4*)(base + NDd);
        x[2] = *(const f32x4*)(base + 4);
        x[3] = *(const f32x4*)(base + NDd + 4);
    };
    auto write_tile = [&](int buf) {
        #pragma unroll
        for (int e2 = 0; e2 < 2; ++e2)
            #pragma unroll
            for (int c = 0; c < 4; ++c) {
                const int n = 8 * g + 4 * e2 + c;
                const int p = ((n & 7) << 4) + (n >> 3);
                const unsigned v = (unsigned)f2bfu(x[2 * e2][c]) |
                                   ((unsigned)f2bfu(x[2 * e2 + 1][c]) << 16);
                *(unsigned*)&lb[buf][p][2 * r2] = v;
            }
    };

    int pj[4];
    #pragma unroll
    for (int j = 0; j < 4; ++j) {
        const int n = nw + j * 16 + l16;
        pj[j] = ((n & 7) << 4) + (n >> 3);
    }

    f32x4 acc[4][4] = {};
    load_tile(0);
    write_tile(0);
    load_tile(32);                          // prefetch tile 1 (distance covers HBM latency)
    for (int it = 0; it < 8; ++it) {
        __syncthreads();
        const int kt = it * 32;
        bf16x8 af[4], bfr[4];
        #pragma unroll
        for (int i = 0; i < 4; ++i)
            af[i] = *(const bf16x8*)(W + (long)(ob + mw + i * 16 + l16) * CCH + kt + quad * 8);
        #pragma unroll
        for (int j = 0; j < 4; ++j)
            bfr[j] = *(const bf16x8*)&lb[it & 1][pj[j]][quad * 8];
        #pragma unroll
        for (int i = 0; i < 4; ++i)
            #pragma unroll
            for (int j = 0; j < 4; ++j)
                acc[i][j] = __builtin_amdgcn_mfma_f32_16x16x32_bf16(af[i], bfr[j], acc[i][j], 0, 0, 0);
        if (it < 7) {
            write_tile((it + 1) & 1);       // stage prefetched regs into the other buffer
            if (it < 6) load_tile((it + 2) * 32);
        }
    }
    #pragma unroll
    for (int i = 0; i < 4; ++i) {
        float bv[4];
        #pragma unroll
        for (int reg = 0; reg < 4; ++reg)
            bv[reg] = b5[z * CCH + ob + mw + i * 16 + quad * 4 + reg];
        #pragma unroll
        for (int j = 0; j < 4; ++j) {
            const int n = nb + nw + j * 16 + l16;
            #pragma unroll
            for (int reg = 0; reg < 4; ++reg)
                O[(long)(ob + mw + i * 16 + quad * 4 + reg) * NDd + n] = acc[i][j][reg] + bv[reg];
        }
    }
}

extern "C" void kernel_launch(void* const* d_in, const int* in_sizes, int n_in,
                              void* d_out, int out_size, void* d_ws, size_t ws_size,
                              hipStream_t stream) {
    const float* detect = (const float*)d_in[0];
    const float* aim    = (const float*)d_in[1];
    const float* g_w    = (const float*)d_in[2];
    const float* g_b    = (const float*)d_in[3];
    const float* th_w   = (const float*)d_in[4];
    const float* th_b   = (const float*)d_in[5];
    const float* phi_w  = (const float*)d_in[6];
    const float* phi_b  = (const float*)d_in[7];
    const float* q_w    = (const float*)d_in[8];
    const float* q_b    = (const float*)d_in[9];
    const float* gamma  = (const float*)d_in[10];
    const float* beta   = (const float*)d_in[11];
    const float* mean   = (const float*)d_in[12];
    const float* var    = (const float*)d_in[13];
    float* out = (float*)d_out;

    float* ws = (float*)d_ws;
    unsigned short* Abf = (unsigned short*)ws;              // 4,194,304 us = 2,097,152 f
    float* r     = ws + 2097152;                            // 1,024
    float* Spart = r + 1024;                                // 8*4*65536 = 2,097,152 f
    unsigned short* ub = (unsigned short*)(Spart + 2097152);
    unsigned short* Shat_u  = ub;                           // 4*320*320 = 409,600 us
    unsigned short* Phat_u  = Shat_u + 409600;              // 256*320   =  81,920 us
    unsigned short* RhatT_u = Phat_u + 81920;               // 320*320   = 102,400 us
    unsigned short* That_u  = RhatT_u + 102400;             // 4*256*320 = 327,680 us
    unsigned short* W5u     = That_u + 327680;              // 4*256*256 = 262,144 us
    float* b5 = (float*)(W5u + 262144);                     // 1,024 f   (total ~19.2 MB)

    k_prep<<<dim3((CCH * PAD + PAD * PAD) / 256), dim3(256), 0, stream>>>(
        q_w, g_w, g_b, th_w, th_b, phi_w, phi_b, Phat_u, RhatT_u);
    k_conv<<<dim3(BB * CCH), dim3(256), 0, stream>>>(aim, Abf, r);
    k_S<<<dim3(4, 4, BB * 8), dim3(64), 0, stream>>>(Abf, Spart);
    k_red<<<dim3(PAD * PAD / 256, BB), dim3(256), 0, stream>>>(Spart, r, Shat_u);
    k_t1<<<dim3(5, 4, BB), dim3(64), 0, stream>>>(Phat_u, Shat_u, That_u);
    k_t2<<<dim3(5, 4, BB), dim3(64), 0, stream>>>(That_u, RhatT_u, q_b, gamma, beta, mean, var, W5u, b5);
    k_final<<<dim3(NDd / 128, CCH / 128, BB), dim3(256), 0, stream>>>(detect, W5u, b5, out);
}